// Round 1
// baseline (342.645 us; speedup 1.0000x reference)
//
#include <hip/hip_runtime.h>
#include <hip/hip_bf16.h>

typedef __attribute__((ext_vector_type(8))) short short8;
typedef __attribute__((ext_vector_type(4))) short short4v;
typedef __attribute__((ext_vector_type(4))) float f32x4;

#define MFMA16(a, b, c) __builtin_amdgcn_mfma_f32_16x16x32_bf16(a, b, c, 0, 0, 0)

__device__ __forceinline__ unsigned short f2bf(float f) {
    unsigned int u = __float_as_uint(f);
    unsigned int r = u + 0x7fffu + ((u >> 16) & 1u);
    return (unsigned short)(r >> 16);
}
__device__ __forceinline__ float bf2f(unsigned short h) {
    return __uint_as_float(((unsigned int)h) << 16);
}

__device__ __forceinline__ void async16(const void* g, void* l) {
    __builtin_amdgcn_global_load_lds(
        (const __attribute__((address_space(1))) unsigned int*)g,
        (__attribute__((address_space(3))) unsigned int*)l, 16, 0, 0);
}

// ---------------- fp32 -> bf16 conversion ----------------
__global__ __launch_bounds__(256) void cvt_kernel(const float* __restrict__ in,
                                                  unsigned short* __restrict__ out,
                                                  int n4) {
    int i = blockIdx.x * 256 + threadIdx.x;
    int stride = gridDim.x * 256;
    for (; i < n4; i += stride) {
        float4 v = reinterpret_cast<const float4*>(in)[i];
        short4v p;
        p[0] = (short)f2bf(v.x); p[1] = (short)f2bf(v.y);
        p[2] = (short)f2bf(v.z); p[3] = (short)f2bf(v.w);
        reinterpret_cast<short4v*>(out)[i] = p;
    }
}

// ---------------- GEMM: C[M,1024] = A[M,1024] @ B[1024,1024]^T + bias ----------------
// MODE 0: elu+1, bf16 out, normal layout [M][1024]        (Q projection)
// MODE 1: elu+1, bf16 out, transposed [n*1024+col][4096]  (K projection -> Kt)
// MODE 2: plain, bf16 out, transposed                     (V projection -> vT)
// MODE 3: plain, fp32 out, normal layout                  (output projection)
template <int MODE>
__global__ __launch_bounds__(256) void gemm_bt(const unsigned short* __restrict__ A,
                                               const unsigned short* __restrict__ B,
                                               const float* __restrict__ bias,
                                               void* __restrict__ out) {
    __shared__ unsigned short As[128 * 32];
    __shared__ unsigned short Bs[128 * 32];
    const int tid = threadIdx.x;
    const int lane = tid & 63, wave = tid >> 6;

    // bijective XCD swizzle (gridDim.x % 8 == 0)
    int nwg = gridDim.x;
    int bid = blockIdx.x;
    int swz = (bid & 7) * (nwg >> 3) + (bid >> 3);
    const int NBN = 8;  // 1024 / 128 column blocks
    int bm = swz / NBN, bn = swz % NBN;
    long row0 = (long)bm * 128;
    long col0 = (long)bn * 128;

    const int lda = 1024;
    const unsigned short* Ag = A + (row0 + (tid >> 2)) * lda + (tid & 3) * 8;
    const unsigned short* Bg = B + (col0 + (tid >> 2)) * lda + (tid & 3) * 8;
    char* AsB = (char*)As + (wave << 10);
    char* BsB = (char*)Bs + (wave << 10);

    const int wr = wave >> 1, wc = wave & 1;  // 64x64 sub-tile per wave
    const int lr = lane & 15, lk = (lane >> 4) << 3;
    const unsigned short* Ard = As + (wr * 64 + lr) * 32 + lk;
    const unsigned short* Brd = Bs + (wc * 64 + lr) * 32 + lk;

    f32x4 acc[4][4] = {};

    for (int k0 = 0; k0 < 1024; k0 += 32) {
        async16(Ag + k0, AsB);
        async16(Ag + k0 + 64 * lda, AsB + 4096);
        async16(Bg + k0, BsB);
        async16(Bg + k0 + 64 * lda, BsB + 4096);
        __syncthreads();
        short8 af[4], bfr[4];
#pragma unroll
        for (int i = 0; i < 4; ++i) af[i] = *(const short8*)(Ard + i * 16 * 32);
#pragma unroll
        for (int i = 0; i < 4; ++i) bfr[i] = *(const short8*)(Brd + i * 16 * 32);
#pragma unroll
        for (int m = 0; m < 4; ++m)
#pragma unroll
            for (int n = 0; n < 4; ++n)
                acc[m][n] = MFMA16(af[m], bfr[n], acc[m][n]);
        __syncthreads();
    }

    // epilogue: C row = row0 + wr*64 + m*16 + (lane>>4)*4 + j ; col = col0 + wc*64 + n*16 + lr
    const int r4 = (lane >> 4) * 4;
#pragma unroll
    for (int m = 0; m < 4; ++m) {
#pragma unroll
        for (int n = 0; n < 4; ++n) {
            long col = col0 + wc * 64 + n * 16 + lr;
            float bcol = bias[col];
            long R0 = row0 + wr * 64 + m * 16 + r4;
            if (MODE == 0) {
                unsigned short* O = (unsigned short*)out;
#pragma unroll
                for (int j = 0; j < 4; ++j) {
                    float v = acc[m][n][j] + bcol;
                    v = v > 0.f ? v + 1.f : __expf(v);
                    O[(R0 + j) * 1024 + col] = f2bf(v);
                }
            } else if (MODE == 1 || MODE == 2) {
                unsigned short* O = (unsigned short*)out;
                long nb = R0 >> 12;
                long s = R0 & 4095;
                short4v pack;
#pragma unroll
                for (int j = 0; j < 4; ++j) {
                    float v = acc[m][n][j] + bcol;
                    if (MODE == 1) v = v > 0.f ? v + 1.f : __expf(v);
                    pack[j] = (short)f2bf(v);
                }
                *(short4v*)(O + ((nb << 10) + col) * 4096 + s) = pack;
            } else {
                float* O = (float*)out;
#pragma unroll
                for (int j = 0; j < 4; ++j)
                    O[(R0 + j) * 1024 + col] = acc[m][n][j] + bcol;
            }
        }
    }
}

// ---------------- KV[n,h,m,d] = sum_s vT[n*1024+h*64+m][s] * Kt[n*1024+h*64+d][s] ----------------
// also Ksum[n*1024+h*64+d] = sum_s Kt[...][s].  Grid: 4*16*8 = 512 blocks (S chunks of 512).
__global__ __launch_bounds__(256) void kv_kernel(const unsigned short* __restrict__ Kt,
                                                 const unsigned short* __restrict__ vT,
                                                 float* __restrict__ KV,
                                                 float* __restrict__ Ksum) {
    int b = blockIdx.x;
    int sc = b & 7, h = (b >> 3) & 15, n = b >> 7;
    const int tid = threadIdx.x, lane = tid & 63, wave = tid >> 6;
    long base = ((long)(n * 1024 + h * 64)) * 4096 + sc * 512;
    const unsigned short* Kp = Kt + base;
    const unsigned short* Vp = vT + base;
    const int lr = lane & 15, lk = (lane >> 4) * 8;

    f32x4 acc[4] = {};
    for (int s0 = 0; s0 < 512; s0 += 32) {
        short8 a = *(const short8*)(Vp + (long)(wave * 16 + lr) * 4096 + s0 + lk);
#pragma unroll
        for (int d4 = 0; d4 < 4; ++d4) {
            short8 bb = *(const short8*)(Kp + (long)(d4 * 16 + lr) * 4096 + s0 + lk);
            acc[d4] = MFMA16(a, bb, acc[d4]);
        }
    }
    float* KVb = KV + (long)(n * 16 + h) * 4096;
#pragma unroll
    for (int d4 = 0; d4 < 4; ++d4)
#pragma unroll
        for (int j = 0; j < 4; ++j) {
            int m = wave * 16 + (lane >> 4) * 4 + j;
            int d = d4 * 16 + lr;
            atomicAdd(KVb + m * 64 + d, acc[d4][j]);
        }
    // Ksum partial: thread t sums 128 s for column d = t&63
    int d = tid & 63, part = tid >> 6;
    const unsigned short* kp2 = Kt + ((long)(n * 1024 + h * 64 + d)) * 4096 + sc * 512 + part * 128;
    float s = 0.f;
    for (int i = 0; i < 128; i += 8) {
        short8 v = *(const short8*)(kp2 + i);
#pragma unroll
        for (int e = 0; e < 8; ++e) s += bf2f((unsigned short)v[e]);
    }
    atomicAdd(Ksum + n * 1024 + h * 64 + d, s);
}

// ---------------- attn: V[n,l,h,m] = (sum_d Q[l,d]*KV[m,d]) / (Q[l,:]·Ksum + eps) ----------------
// grid 4*16*32 = 2048 blocks; block handles 128 l-rows of one (n,h).
__global__ __launch_bounds__(256) void attn_kernel(const unsigned short* __restrict__ Qm,
                                                   const float* __restrict__ KV,
                                                   const float* __restrict__ Ksum,
                                                   unsigned short* __restrict__ Vbuf) {
    __shared__ unsigned short Qs[128 * 64];
    __shared__ unsigned short KVs[64 * 64];
    __shared__ float zin[128];
    __shared__ float ks[64];
    int b = blockIdx.x;
    int lc = b & 31, h = (b >> 5) & 15, n = b >> 9;
    int tid = threadIdx.x, lane = tid & 63, wave = tid >> 6;
    long l0 = (long)n * 4096 + lc * 128;

    const unsigned short* Qg = Qm + (l0 + (tid >> 3)) * 1024 + h * 64 + (tid & 7) * 8;
    char* QsB = (char*)Qs + (wave << 10);
#pragma unroll
    for (int it = 0; it < 4; ++it)
        async16(Qg + (long)it * 32 * 1024, QsB + it * 4096);

    const float* kvp = KV + (long)(n * 16 + h) * 4096;
    for (int i = tid * 4; i < 4096; i += 1024) {
        float4 v = *reinterpret_cast<const float4*>(kvp + i);
        short4v p;
        p[0] = (short)f2bf(v.x); p[1] = (short)f2bf(v.y);
        p[2] = (short)f2bf(v.z); p[3] = (short)f2bf(v.w);
        *(short4v*)(KVs + i) = p;
    }
    if (tid < 64) ks[tid] = Ksum[n * 1024 + h * 64 + tid];
    __syncthreads();

    if (tid < 128) {
        float den = 0.f;
        const unsigned short* qrow = Qs + tid * 64;
#pragma unroll
        for (int d = 0; d < 64; ++d) den += bf2f(qrow[d]) * ks[d];
        zin[tid] = 1.0f / (den + 1e-6f);
    }
    __syncthreads();

    const int lr = lane & 15, lk = (lane >> 4) * 8;
    f32x4 acc[2][4] = {};
#pragma unroll
    for (int kk = 0; kk < 2; ++kk) {
        short8 a0 = *(const short8*)(Qs + (wave * 32 + lr) * 64 + kk * 32 + lk);
        short8 a1 = *(const short8*)(Qs + (wave * 32 + 16 + lr) * 64 + kk * 32 + lk);
#pragma unroll
        for (int nn = 0; nn < 4; ++nn) {
            short8 bb = *(const short8*)(KVs + (nn * 16 + lr) * 64 + kk * 32 + lk);
            acc[0][nn] = MFMA16(a0, bb, acc[0][nn]);
            acc[1][nn] = MFMA16(a1, bb, acc[1][nn]);
        }
    }
#pragma unroll
    for (int mi = 0; mi < 2; ++mi)
#pragma unroll
        for (int nn = 0; nn < 4; ++nn)
#pragma unroll
            for (int j = 0; j < 4; ++j) {
                int rl = wave * 32 + mi * 16 + (lane >> 4) * 4 + j;
                int mcol = nn * 16 + lr;
                float v = acc[mi][nn][j] * zin[rl];
                Vbuf[(l0 + rl) * 1024 + h * 64 + mcol] = f2bf(v);
            }
}

extern "C" void kernel_launch(void* const* d_in, const int* in_sizes, int n_in,
                              void* d_out, int out_size, void* d_ws, size_t ws_size,
                              hipStream_t stream) {
    const float* queries = (const float*)d_in[0];
    const float* keys    = (const float*)d_in[1];
    const float* values  = (const float*)d_in[2];
    const float* Wq = (const float*)d_in[3];
    const float* bq = (const float*)d_in[4];
    const float* Wk = (const float*)d_in[5];
    const float* bk = (const float*)d_in[6];
    const float* Wv = (const float*)d_in[7];
    const float* bv = (const float*)d_in[8];
    const float* Wo = (const float*)d_in[9];
    const float* bo = (const float*)d_in[10];
    float* out = (float*)d_out;

    char* ws = (char*)d_ws;
    const size_t SZ = (size_t)16384 * 1024 * 2;  // 33.5 MB bf16 matrix
    const size_t WSZ = (size_t)1024 * 1024 * 2;  // 2 MB bf16 weight
    unsigned short* qb  = (unsigned short*)(ws);
    unsigned short* kb  = (unsigned short*)(ws + SZ);
    unsigned short* vb  = (unsigned short*)(ws + 2 * SZ);
    unsigned short* Wqb = (unsigned short*)(ws + 3 * SZ);
    unsigned short* Wkb = (unsigned short*)(ws + 3 * SZ + WSZ);
    unsigned short* Wvb = (unsigned short*)(ws + 3 * SZ + 2 * WSZ);
    unsigned short* Wob = (unsigned short*)(ws + 3 * SZ + 3 * WSZ);
    unsigned short* Qm  = (unsigned short*)(ws + 3 * SZ + 4 * WSZ);
    unsigned short* Kt  = (unsigned short*)(ws + 4 * SZ + 4 * WSZ);
    unsigned short* vT  = (unsigned short*)(ws + 5 * SZ + 4 * WSZ);
    float* KVf = (float*)(ws + 6 * SZ + 4 * WSZ);
    float* Ksf = (float*)(ws + 6 * SZ + 4 * WSZ + 1048576);
    unsigned short* Vbuf = qb;  // alias: qb dead after Q projection

    const int n4big = 16384 * 1024 / 4;
    const int n4w = 1024 * 1024 / 4;
    cvt_kernel<<<2048, 256, 0, stream>>>(queries, qb, n4big);
    cvt_kernel<<<2048, 256, 0, stream>>>(keys, kb, n4big);
    cvt_kernel<<<2048, 256, 0, stream>>>(values, vb, n4big);
    cvt_kernel<<<256, 256, 0, stream>>>(Wq, Wqb, n4w);
    cvt_kernel<<<256, 256, 0, stream>>>(Wk, Wkb, n4w);
    cvt_kernel<<<256, 256, 0, stream>>>(Wv, Wvb, n4w);
    cvt_kernel<<<256, 256, 0, stream>>>(Wo, Wob, n4w);

    gemm_bt<0><<<1024, 256, 0, stream>>>(qb, Wqb, bq, Qm);
    gemm_bt<1><<<1024, 256, 0, stream>>>(kb, Wkb, bk, Kt);
    gemm_bt<2><<<1024, 256, 0, stream>>>(vb, Wvb, bv, vT);

    hipMemsetAsync(KVf, 0, 1048576 + 16384, stream);
    kv_kernel<<<512, 256, 0, stream>>>(Kt, vT, KVf, Ksf);
    attn_kernel<<<2048, 256, 0, stream>>>(Qm, KVf, Ksf, Vbuf);

    gemm_bt<3><<<1024, 256, 0, stream>>>(Vbuf, Wob, bo, out);
}

// Round 2
// 294.379 us; speedup vs baseline: 1.1640x; 1.1640x over previous
//
#include <hip/hip_runtime.h>
#include <hip/hip_bf16.h>

typedef __attribute__((ext_vector_type(8))) short short8;
typedef __attribute__((ext_vector_type(4))) short short4v;
typedef __attribute__((ext_vector_type(4))) float f32x4;

#define MFMA16(a, b, c) __builtin_amdgcn_mfma_f32_16x16x32_bf16(a, b, c, 0, 0, 0)

__device__ __forceinline__ unsigned short f2bf(float f) {
    unsigned int u = __float_as_uint(f);
    unsigned int r = u + 0x7fffu + ((u >> 16) & 1u);
    return (unsigned short)(r >> 16);
}
__device__ __forceinline__ float bf2f(unsigned short h) {
    return __uint_as_float(((unsigned int)h) << 16);
}

__device__ __forceinline__ void async16(const void* g, void* l) {
    __builtin_amdgcn_global_load_lds(
        (const __attribute__((address_space(1))) unsigned int*)g,
        (__attribute__((address_space(3))) unsigned int*)l, 16, 0, 0);
}

#define S_BARRIER() asm volatile("s_barrier" ::: "memory")
#define WAIT_LGKM0() do { asm volatile("s_waitcnt lgkmcnt(0)" ::: "memory"); \
                          __builtin_amdgcn_sched_barrier(0); } while (0)

// ---------------- fp32 -> bf16 conversion ----------------
__global__ __launch_bounds__(256) void cvt_kernel(const float* __restrict__ in,
                                                  unsigned short* __restrict__ out,
                                                  int n4) {
    int i = blockIdx.x * 256 + threadIdx.x;
    int stride = gridDim.x * 256;
    for (; i < n4; i += stride) {
        float4 v = reinterpret_cast<const float4*>(in)[i];
        short4v p;
        p[0] = (short)f2bf(v.x); p[1] = (short)f2bf(v.y);
        p[2] = (short)f2bf(v.z); p[3] = (short)f2bf(v.w);
        reinterpret_cast<short4v*>(out)[i] = p;
    }
}

// ---------------- 256x256-tile GEMM: C[M,1024] = A[M,1024] @ B[1024,1024]^T + bias --------
// 512 threads = 8 waves (2 Mx4 N), per-wave 128x64 output, BK=32, 4-deep LDS pipeline,
// counted vmcnt(8) (tiles t+2,t+3 in flight), XOR chunk swizzle (both sides).
// MODE 0: elu+1, bf16 out, normal layout [M][1024]        (Q projection)
// MODE 1: elu+1, bf16 out, transposed [n*1024+col][4096]  (K projection -> Kt)
// MODE 2: plain, bf16 out, transposed                     (V projection -> vT)
// MODE 3: plain, fp32 out, normal layout                  (output projection)
template <int MODE>
__global__ __launch_bounds__(512, 2) void gemm256(const unsigned short* __restrict__ A,
                                                  const unsigned short* __restrict__ B,
                                                  const float* __restrict__ bias,
                                                  void* __restrict__ out) {
    // 4 buffers per operand, each 256 rows x 32 bf16 (16KB). Total 128KB.
    __shared__ unsigned short As[4][8192];
    __shared__ unsigned short Bs[4][8192];

    const int tid = threadIdx.x;           // 0..511
    const int lane = tid & 63, wid = tid >> 6;
    const int wr = wid >> 2, wc = wid & 3; // wave tile: rows wr*128, cols wc*64
    const int lr = lane & 15, lg = lane >> 4;

    // XCD-aware bijective swizzle (gridDim.x == 256, %8==0)
    int nwg = gridDim.x;
    int bid = blockIdx.x;
    int swz = (bid & 7) * (nwg >> 3) + (bid >> 3);
    int bm = swz >> 2, bn = swz & 3;       // N/256 = 4 column blocks
    long row0 = (long)bm * 256;
    long col0 = (long)bn * 256;

    // ---- staging addresses (pre-swizzled global source; LDS dest linear) ----
    // thread stages rows r = sr0 (+128), stored chunk sc; data chunk = sc ^ (r&3)
    const int sr0 = tid >> 2;
    const int sc = tid & 3;
    const int kel = ((sc ^ (sr0 & 3)) << 3);  // element offset of data chunk in k-tile
    const unsigned short* Ag = A + (row0 + sr0) * 1024 + kel;
    const unsigned short* Bg = B + (col0 + sr0) * 1024 + kel;

#define STAGE_A(t) do { char* d_ = (char*)As[(t) & 3] + tid * 16;            \
        async16(Ag + (t) * 32, d_);                                          \
        async16(Ag + 128 * 1024 + (t) * 32, d_ + 8192); } while (0)
#define STAGE_B(t) do { char* d_ = (char*)Bs[(t) & 3] + tid * 16;            \
        async16(Bg + (t) * 32, d_);                                          \
        async16(Bg + 128 * 1024 + (t) * 32, d_ + 8192); } while (0)

    // ---- ds_read fragment addresses (swizzled chunk: lg ^ (row&3), row&3 == lr&3) ----
    const int xch = ((lr & 3) ^ lg) << 3;
    const unsigned short* Ard = &As[0][0] + (wr * 128 + lr) * 32 + xch;
    const unsigned short* Brd = &Bs[0][0] + (wc * 64 + lr) * 32 + xch;

    f32x4 acc[8][4] = {};
    short8 af[4], bfr[4];

    // prologue: stage tiles 0,1,2 ; wait tile 0 (allow 8 outstanding = tiles 1,2)
    STAGE_A(0); STAGE_B(0);
    STAGE_A(1); STAGE_B(1);
    STAGE_A(2); STAGE_B(2);
    asm volatile("s_waitcnt vmcnt(8)" ::: "memory");
    __builtin_amdgcn_sched_barrier(0);
    S_BARRIER();

#pragma unroll 4
    for (int t = 0; t < 32; ++t) {
        const unsigned short* Ab = Ard + (t & 3) * 8192;
        const unsigned short* Bb = Brd + (t & 3) * 8192;
        // ---- phase 0: rows m0..3 x all n ----
#pragma unroll
        for (int m = 0; m < 4; ++m) af[m] = *(const short8*)(Ab + m * 512);
#pragma unroll
        for (int n = 0; n < 4; ++n) bfr[n] = *(const short8*)(Bb + n * 512);
        if (t + 3 < 32) STAGE_A(t + 3);
        S_BARRIER();
        WAIT_LGKM0();
        __builtin_amdgcn_s_setprio(1);
#pragma unroll
        for (int m = 0; m < 4; ++m)
#pragma unroll
            for (int n = 0; n < 4; ++n)
                acc[m][n] = MFMA16(af[m], bfr[n], acc[m][n]);
        __builtin_amdgcn_s_setprio(0);
        __builtin_amdgcn_sched_barrier(0);
        S_BARRIER();
        // ---- phase 1: rows m4..7 x all n ----
#pragma unroll
        for (int m = 0; m < 4; ++m) af[m] = *(const short8*)(Ab + (m + 4) * 512);
        if (t + 3 < 32) STAGE_B(t + 3);
        if (t < 29) {
            asm volatile("s_waitcnt vmcnt(8)" ::: "memory");  // tile t+1 landed
        } else {
            asm volatile("s_waitcnt vmcnt(0)" ::: "memory");  // tail drain
        }
        __builtin_amdgcn_sched_barrier(0);
        S_BARRIER();
        WAIT_LGKM0();
        __builtin_amdgcn_s_setprio(1);
#pragma unroll
        for (int m = 0; m < 4; ++m)
#pragma unroll
            for (int n = 0; n < 4; ++n)
                acc[m + 4][n] = MFMA16(af[m], bfr[n], acc[m + 4][n]);
        __builtin_amdgcn_s_setprio(0);
        __builtin_amdgcn_sched_barrier(0);
        S_BARRIER();
    }
#undef STAGE_A
#undef STAGE_B

    // ---- epilogue ----
    const int r4 = lg * 4;
#pragma unroll
    for (int m = 0; m < 8; ++m) {
#pragma unroll
        for (int n = 0; n < 4; ++n) {
            long col = col0 + wc * 64 + n * 16 + lr;
            float bcol = bias[col];
            long R0 = row0 + wr * 128 + m * 16 + r4;
            if (MODE == 0) {
                unsigned short* O = (unsigned short*)out;
#pragma unroll
                for (int j = 0; j < 4; ++j) {
                    float v = acc[m][n][j] + bcol;
                    v = v > 0.f ? v + 1.f : __expf(v);
                    O[(R0 + j) * 1024 + col] = f2bf(v);
                }
            } else if (MODE == 1 || MODE == 2) {
                unsigned short* O = (unsigned short*)out;
                long nb = R0 >> 12;
                long s = R0 & 4095;
                short4v pack;
#pragma unroll
                for (int j = 0; j < 4; ++j) {
                    float v = acc[m][n][j] + bcol;
                    if (MODE == 1) v = v > 0.f ? v + 1.f : __expf(v);
                    pack[j] = (short)f2bf(v);
                }
                *(short4v*)(O + ((nb << 10) + col) * 4096 + s) = pack;
            } else {
                float* O = (float*)out;
#pragma unroll
                for (int j = 0; j < 4; ++j)
                    O[(R0 + j) * 1024 + col] = acc[m][n][j] + bcol;
            }
        }
    }
}

// ---------------- KV[n,h,m,d] = sum_s vT[n*1024+h*64+m][s] * Kt[n*1024+h*64+d][s] ----------------
// also Ksum[n*1024+h*64+d] = sum_s Kt[...][s].  Grid: 4*16*8 = 512 blocks (S chunks of 512).
__global__ __launch_bounds__(256) void kv_kernel(const unsigned short* __restrict__ Kt,
                                                 const unsigned short* __restrict__ vT,
                                                 float* __restrict__ KV,
                                                 float* __restrict__ Ksum) {
    int b = blockIdx.x;
    int sc = b & 7, h = (b >> 3) & 15, n = b >> 7;
    const int tid = threadIdx.x, lane = tid & 63, wave = tid >> 6;
    long base = ((long)(n * 1024 + h * 64)) * 4096 + sc * 512;
    const unsigned short* Kp = Kt + base;
    const unsigned short* Vp = vT + base;
    const int lr = lane & 15, lk = (lane >> 4) * 8;

    f32x4 acc[4] = {};
    for (int s0 = 0; s0 < 512; s0 += 32) {
        short8 a = *(const short8*)(Vp + (long)(wave * 16 + lr) * 4096 + s0 + lk);
#pragma unroll
        for (int d4 = 0; d4 < 4; ++d4) {
            short8 bb = *(const short8*)(Kp + (long)(d4 * 16 + lr) * 4096 + s0 + lk);
            acc[d4] = MFMA16(a, bb, acc[d4]);
        }
    }
    float* KVb = KV + (long)(n * 16 + h) * 4096;
#pragma unroll
    for (int d4 = 0; d4 < 4; ++d4)
#pragma unroll
        for (int j = 0; j < 4; ++j) {
            int m = wave * 16 + (lane >> 4) * 4 + j;
            int d = d4 * 16 + lr;
            atomicAdd(KVb + m * 64 + d, acc[d4][j]);
        }
    // Ksum partial: thread t sums 128 s for column d = t&63
    int d = tid & 63, part = tid >> 6;
    const unsigned short* kp2 = Kt + ((long)(n * 1024 + h * 64 + d)) * 4096 + sc * 512 + part * 128;
    float s = 0.f;
    for (int i = 0; i < 128; i += 8) {
        short8 v = *(const short8*)(kp2 + i);
#pragma unroll
        for (int e = 0; e < 8; ++e) s += bf2f((unsigned short)v[e]);
    }
    atomicAdd(Ksum + n * 1024 + h * 64 + d, s);
}

// ---------------- attn: V[n,l,h,m] = (sum_d Q[l,d]*KV[m,d]) / (Q[l,:]·Ksum + eps) ----------------
__global__ __launch_bounds__(256) void attn_kernel(const unsigned short* __restrict__ Qm,
                                                   const float* __restrict__ KV,
                                                   const float* __restrict__ Ksum,
                                                   unsigned short* __restrict__ Vbuf) {
    __shared__ unsigned short Qs[128 * 64];
    __shared__ unsigned short KVs[64 * 64];
    __shared__ float zin[128];
    __shared__ float ks[64];
    int b = blockIdx.x;
    int lc = b & 31, h = (b >> 5) & 15, n = b >> 9;
    int tid = threadIdx.x, lane = tid & 63, wave = tid >> 6;
    long l0 = (long)n * 4096 + lc * 128;

    const unsigned short* Qg = Qm + (l0 + (tid >> 3)) * 1024 + h * 64 + (tid & 7) * 8;
    char* QsB = (char*)Qs + (wave << 10);
#pragma unroll
    for (int it = 0; it < 4; ++it)
        async16(Qg + (long)it * 32 * 1024, QsB + it * 4096);

    const float* kvp = KV + (long)(n * 16 + h) * 4096;
    for (int i = tid * 4; i < 4096; i += 1024) {
        float4 v = *reinterpret_cast<const float4*>(kvp + i);
        short4v p;
        p[0] = (short)f2bf(v.x); p[1] = (short)f2bf(v.y);
        p[2] = (short)f2bf(v.z); p[3] = (short)f2bf(v.w);
        *(short4v*)(KVs + i) = p;
    }
    if (tid < 64) ks[tid] = Ksum[n * 1024 + h * 64 + tid];
    __syncthreads();

    if (tid < 128) {
        float den = 0.f;
        const unsigned short* qrow = Qs + tid * 64;
#pragma unroll
        for (int d = 0; d < 64; ++d) den += bf2f(qrow[d]) * ks[d];
        zin[tid] = 1.0f / (den + 1e-6f);
    }
    __syncthreads();

    const int lr = lane & 15, lk = (lane >> 4) * 8;
    f32x4 acc[2][4] = {};
#pragma unroll
    for (int kk = 0; kk < 2; ++kk) {
        short8 a0 = *(const short8*)(Qs + (wave * 32 + lr) * 64 + kk * 32 + lk);
        short8 a1 = *(const short8*)(Qs + (wave * 32 + 16 + lr) * 64 + kk * 32 + lk);
#pragma unroll
        for (int nn = 0; nn < 4; ++nn) {
            short8 bb = *(const short8*)(KVs + (nn * 16 + lr) * 64 + kk * 32 + lk);
            acc[0][nn] = MFMA16(a0, bb, acc[0][nn]);
            acc[1][nn] = MFMA16(a1, bb, acc[1][nn]);
        }
    }
#pragma unroll
    for (int mi = 0; mi < 2; ++mi)
#pragma unroll
        for (int nn = 0; nn < 4; ++nn)
#pragma unroll
            for (int j = 0; j < 4; ++j) {
                int rl = wave * 32 + mi * 16 + (lane >> 4) * 4 + j;
                int mcol = nn * 16 + lr;
                float v = acc[mi][nn][j] * zin[rl];
                Vbuf[(l0 + rl) * 1024 + h * 64 + mcol] = f2bf(v);
            }
}

extern "C" void kernel_launch(void* const* d_in, const int* in_sizes, int n_in,
                              void* d_out, int out_size, void* d_ws, size_t ws_size,
                              hipStream_t stream) {
    const float* queries = (const float*)d_in[0];
    const float* keys    = (const float*)d_in[1];
    const float* values  = (const float*)d_in[2];
    const float* Wq = (const float*)d_in[3];
    const float* bq = (const float*)d_in[4];
    const float* Wk = (const float*)d_in[5];
    const float* bk = (const float*)d_in[6];
    const float* Wv = (const float*)d_in[7];
    const float* bv = (const float*)d_in[8];
    const float* Wo = (const float*)d_in[9];
    const float* bo = (const float*)d_in[10];
    float* out = (float*)d_out;

    char* ws = (char*)d_ws;
    const size_t SZ = (size_t)16384 * 1024 * 2;  // 33.5 MB bf16 matrix
    const size_t WSZ = (size_t)1024 * 1024 * 2;  // 2 MB bf16 weight
    unsigned short* qb  = (unsigned short*)(ws);
    unsigned short* kb  = (unsigned short*)(ws + SZ);
    unsigned short* vb  = (unsigned short*)(ws + 2 * SZ);
    unsigned short* Wqb = (unsigned short*)(ws + 3 * SZ);
    unsigned short* Wkb = (unsigned short*)(ws + 3 * SZ + WSZ);
    unsigned short* Wvb = (unsigned short*)(ws + 3 * SZ + 2 * WSZ);
    unsigned short* Wob = (unsigned short*)(ws + 3 * SZ + 3 * WSZ);
    unsigned short* Qm  = (unsigned short*)(ws + 3 * SZ + 4 * WSZ);
    unsigned short* Kt  = (unsigned short*)(ws + 4 * SZ + 4 * WSZ);
    unsigned short* vT  = (unsigned short*)(ws + 5 * SZ + 4 * WSZ);
    float* KVf = (float*)(ws + 6 * SZ + 4 * WSZ);
    float* Ksf = (float*)(ws + 6 * SZ + 4 * WSZ + 1048576);
    unsigned short* Vbuf = qb;  // alias: qb dead after Q projection

    const int n4big = 16384 * 1024 / 4;
    const int n4w = 1024 * 1024 / 4;
    cvt_kernel<<<2048, 256, 0, stream>>>(queries, qb, n4big);
    cvt_kernel<<<2048, 256, 0, stream>>>(keys, kb, n4big);
    cvt_kernel<<<2048, 256, 0, stream>>>(values, vb, n4big);
    cvt_kernel<<<256, 256, 0, stream>>>(Wq, Wqb, n4w);
    cvt_kernel<<<256, 256, 0, stream>>>(Wk, Wkb, n4w);
    cvt_kernel<<<256, 256, 0, stream>>>(Wv, Wvb, n4w);
    cvt_kernel<<<256, 256, 0, stream>>>(Wo, Wob, n4w);

    gemm256<0><<<256, 512, 0, stream>>>(qb, Wqb, bq, Qm);
    gemm256<1><<<256, 512, 0, stream>>>(kb, Wkb, bk, Kt);
    gemm256<2><<<256, 512, 0, stream>>>(vb, Wvb, bv, vT);

    hipMemsetAsync(KVf, 0, 1048576 + 16384, stream);
    kv_kernel<<<512, 256, 0, stream>>>(Kt, vT, KVf, Ksf);
    attn_kernel<<<2048, 256, 0, stream>>>(Qm, KVf, Ksf, Vbuf);

    gemm256<3><<<256, 512, 0, stream>>>(Vbuf, Wob, bo, out);
}

// Round 4
// 293.395 us; speedup vs baseline: 1.1679x; 1.0034x over previous
//
#include <hip/hip_runtime.h>
#include <hip/hip_bf16.h>

typedef __attribute__((ext_vector_type(8))) short short8;
typedef __attribute__((ext_vector_type(4))) short short4v;
typedef __attribute__((ext_vector_type(4))) float f32x4;

#define MFMA16(a, b, c) __builtin_amdgcn_mfma_f32_16x16x32_bf16(a, b, c, 0, 0, 0)

__device__ __forceinline__ unsigned short f2bf(float f) {
    unsigned int u = __float_as_uint(f);
    unsigned int r = u + 0x7fffu + ((u >> 16) & 1u);
    return (unsigned short)(r >> 16);
}
__device__ __forceinline__ float bf2f(unsigned short h) {
    return __uint_as_float(((unsigned int)h) << 16);
}

__device__ __forceinline__ void async16(const void* g, void* l) {
    __builtin_amdgcn_global_load_lds(
        (const __attribute__((address_space(1))) unsigned int*)g,
        (__attribute__((address_space(3))) unsigned int*)l, 16, 0, 0);
}

#define S_BARRIER() asm volatile("s_barrier" ::: "memory")
#define SCHED_FENCE() __builtin_amdgcn_sched_barrier(0)

// ---------------- fp32 -> bf16 conversion ----------------
__global__ __launch_bounds__(256) void cvt_kernel(const float* __restrict__ in,
                                                  unsigned short* __restrict__ out,
                                                  int n4) {
    int i = blockIdx.x * 256 + threadIdx.x;
    int stride = gridDim.x * 256;
    for (; i < n4; i += stride) {
        float4 v = reinterpret_cast<const float4*>(in)[i];
        short4v p;
        p[0] = (short)f2bf(v.x); p[1] = (short)f2bf(v.y);
        p[2] = (short)f2bf(v.z); p[3] = (short)f2bf(v.w);
        reinterpret_cast<short4v*>(out)[i] = p;
    }
}

// ---------------- GEMM: C[M,1024] = A[M,1024] @ B[1024,1024]^T + bias ----------------
// BM=256, BN=128, BK=64. 512 threads = 8 waves (4M x 2N), per-wave 64x64 output.
// 3-buffer LDS pipeline (48KB each): during tile t, stage tile t+2 into buf[(t+2)%3]
// (freed 2 tiles ago -> no race); boundary wait = vmcnt(6) (tile t+1 provably landed,
// t+2's 6 loads stay in flight) + one s_barrier per tile. Full 3-bit XOR chunk swizzle
// (chunk ^= row&7) on 128B rows -> conflict-free ds_read_b128.
// MODE 0: elu+1, bf16 out, normal layout [M][1024]        (Q projection)
// MODE 1: elu+1, bf16 out, transposed [n*1024+col][4096]  (K projection -> Kt)
// MODE 2: plain, bf16 out, transposed                     (V projection -> vT)
// MODE 3: plain, fp32 out, normal layout                  (output projection)
template <int MODE>
__global__ __launch_bounds__(512, 1) void gemm3p(const unsigned short* __restrict__ A,
                                                 const unsigned short* __restrict__ B,
                                                 const float* __restrict__ bias,
                                                 void* __restrict__ out) {
    __shared__ char lds[3 * 49152];  // per buf: A 32768 B, B 16384 B

    const int tid = threadIdx.x;            // 0..511
    const int lane = tid & 63, wid = tid >> 6;
    const int wr = wid >> 1, wc = wid & 1;  // wave tile: rows wr*64, cols wc*64
    const int lr = lane & 15, lg = lane >> 4;

    // XCD-aware bijective swizzle; XCD x gets bm in [8x,8x+8) with all bn -> L2 A-reuse
    const int nwg = gridDim.x;              // 512
    const int bid = blockIdx.x;
    const int swz = (bid & 7) * (nwg >> 3) + (bid >> 3);
    const int bm = swz >> 3, bn = swz & 7;
    const long row0 = (long)bm * 256;
    const long col0 = (long)bn * 128;

    // ---- staging sources (pre-swizzled: data chunk = stored chunk ^ (row&7)) ----
    const unsigned short* asrc[4];
    const unsigned short* bsrc[2];
#pragma unroll
    for (int i = 0; i < 4; ++i) {
        int s = i * 512 + tid, r = s >> 3, c = s & 7;
        asrc[i] = A + (row0 + r) * 1024 + ((c ^ (r & 7)) << 3);
    }
#pragma unroll
    for (int i = 0; i < 2; ++i) {
        int s = i * 512 + tid, r = s >> 3, c = s & 7;
        bsrc[i] = B + (col0 + r) * 1024 + ((c ^ (r & 7)) << 3);
    }
    const int dst = tid * 16;

#define STG_A3(buf, t) do {                                   \
        async16(asrc[0] + (t) * 64, (buf) + dst);             \
        async16(asrc[1] + (t) * 64, (buf) + 8192 + dst);      \
        async16(asrc[2] + (t) * 64, (buf) + 16384 + dst); } while (0)
#define STG_B3(buf, t) do {                                   \
        async16(asrc[3] + (t) * 64, (buf) + 24576 + dst);     \
        async16(bsrc[0] + (t) * 64, (buf) + 32768 + dst);     \
        async16(bsrc[1] + (t) * 64, (buf) + 40960 + dst); } while (0)

    // ---- ds_read offsets (swizzled chunk: (kk*4+lg) ^ (row&7), row&7 == lr&7) ----
    const int offA0 = (wr * 64 + lr) * 128 + (((0 + lg) ^ (lr & 7)) << 4);
    const int offA1 = (wr * 64 + lr) * 128 + (((4 + lg) ^ (lr & 7)) << 4);
    const int offB0 = 32768 + (wc * 64 + lr) * 128 + (((0 + lg) ^ (lr & 7)) << 4);
    const int offB1 = 32768 + (wc * 64 + lr) * 128 + (((4 + lg) ^ (lr & 7)) << 4);

    f32x4 acc[4][4] = {};

    char* p0 = lds;            // tile t   (read)
    char* p1 = lds + 49152;    // tile t+1 (landed-or-inflight)
    char* p2 = lds + 98304;    // tile t+2 (stage target)

    // prologue: stage tiles 0,1; wait tile 0 (6 of tile 1 stay outstanding)
    STG_A3(p0, 0); STG_B3(p0, 0);
    STG_A3(p1, 1); STG_B3(p1, 1);
    asm volatile("s_waitcnt vmcnt(6)" ::: "memory");
    SCHED_FENCE();
    S_BARRIER();

#pragma unroll
    for (int t = 0; t < 16; ++t) {
        short8 a0[4], b0[4], a1[4], b1[4];
#pragma unroll
        for (int m = 0; m < 4; ++m) a0[m] = *(const short8*)(p0 + offA0 + m * 2048);
#pragma unroll
        for (int n = 0; n < 4; ++n) b0[n] = *(const short8*)(p0 + offB0 + n * 2048);
        if (t < 14) STG_A3(p2, t + 2);
#pragma unroll
        for (int m = 0; m < 4; ++m) a1[m] = *(const short8*)(p0 + offA1 + m * 2048);
#pragma unroll
        for (int n = 0; n < 4; ++n) b1[n] = *(const short8*)(p0 + offB1 + n * 2048);
        if (t < 14) STG_B3(p2, t + 2);

        asm volatile("s_waitcnt lgkmcnt(8)" ::: "memory");  // kk0 frags landed
        SCHED_FENCE();
        __builtin_amdgcn_s_setprio(1);
#pragma unroll
        for (int m = 0; m < 4; ++m)
#pragma unroll
            for (int n = 0; n < 4; ++n)
                acc[m][n] = MFMA16(a0[m], b0[n], acc[m][n]);
        __builtin_amdgcn_s_setprio(0);
        asm volatile("s_waitcnt lgkmcnt(0)" ::: "memory");  // kk1 frags landed
        SCHED_FENCE();
        __builtin_amdgcn_s_setprio(1);
#pragma unroll
        for (int m = 0; m < 4; ++m)
#pragma unroll
            for (int n = 0; n < 4; ++n)
                acc[m][n] = MFMA16(a1[m], b1[n], acc[m][n]);
        __builtin_amdgcn_s_setprio(0);
        SCHED_FENCE();
        // boundary: tile t+1 must be fully landed; keep t+2's 6 loads in flight
        if (t < 14) {
            asm volatile("s_waitcnt vmcnt(6)" ::: "memory");
        } else {
            asm volatile("s_waitcnt vmcnt(0)" ::: "memory");  // cheap tail drain
        }
        SCHED_FENCE();
        S_BARRIER();
        char* tmp = p0; p0 = p1; p1 = p2; p2 = tmp;  // rotate buffers
    }
#undef STG_A3
#undef STG_B3

    // ---- epilogue ----
    const int r4 = lg * 4;
#pragma unroll
    for (int m = 0; m < 4; ++m) {
#pragma unroll
        for (int n = 0; n < 4; ++n) {
            long col = col0 + wc * 64 + n * 16 + lr;
            float bcol = bias[col];
            long R0 = row0 + wr * 64 + m * 16 + r4;
            if (MODE == 0) {
                unsigned short* O = (unsigned short*)out;
#pragma unroll
                for (int j = 0; j < 4; ++j) {
                    float v = acc[m][n][j] + bcol;
                    v = v > 0.f ? v + 1.f : __expf(v);
                    O[(R0 + j) * 1024 + col] = f2bf(v);
                }
            } else if (MODE == 1 || MODE == 2) {
                unsigned short* O = (unsigned short*)out;
                long nb = R0 >> 12;
                long s = R0 & 4095;
                short4v pack;
#pragma unroll
                for (int j = 0; j < 4; ++j) {
                    float v = acc[m][n][j] + bcol;
                    if (MODE == 1) v = v > 0.f ? v + 1.f : __expf(v);
                    pack[j] = (short)f2bf(v);
                }
                *(short4v*)(O + ((nb << 10) + col) * 4096 + s) = pack;
            } else {
                float* O = (float*)out;
#pragma unroll
                for (int j = 0; j < 4; ++j)
                    O[(R0 + j) * 1024 + col] = acc[m][n][j] + bcol;
            }
        }
    }
}

// ---------------- KV[n,h,m,d] = sum_s vT[n*1024+h*64+m][s] * Kt[n*1024+h*64+d][s] ----------------
// also Ksum[n*1024+h*64+d] = sum_s Kt[...][s].  Grid: 4*16*8 = 512 blocks (S chunks of 512).
__global__ __launch_bounds__(256) void kv_kernel(const unsigned short* __restrict__ Kt,
                                                 const unsigned short* __restrict__ vT,
                                                 float* __restrict__ KV,
                                                 float* __restrict__ Ksum) {
    int b = blockIdx.x;
    int sc = b & 7, h = (b >> 3) & 15, n = b >> 7;
    const int tid = threadIdx.x, lane = tid & 63, wave = tid >> 6;
    long base = ((long)(n * 1024 + h * 64)) * 4096 + sc * 512;
    const unsigned short* Kp = Kt + base;
    const unsigned short* Vp = vT + base;
    const int lr = lane & 15, lk = (lane >> 4) * 8;

    f32x4 acc[4] = {};
    for (int s0 = 0; s0 < 512; s0 += 32) {
        short8 a = *(const short8*)(Vp + (long)(wave * 16 + lr) * 4096 + s0 + lk);
#pragma unroll
        for (int d4 = 0; d4 < 4; ++d4) {
            short8 bb = *(const short8*)(Kp + (long)(d4 * 16 + lr) * 4096 + s0 + lk);
            acc[d4] = MFMA16(a, bb, acc[d4]);
        }
    }
    float* KVb = KV + (long)(n * 16 + h) * 4096;
#pragma unroll
    for (int d4 = 0; d4 < 4; ++d4)
#pragma unroll
        for (int j = 0; j < 4; ++j) {
            int m = wave * 16 + (lane >> 4) * 4 + j;
            int d = d4 * 16 + lr;
            atomicAdd(KVb + m * 64 + d, acc[d4][j]);
        }
    // Ksum partial: thread t sums 128 s for column d = t&63
    int d = tid & 63, part = tid >> 6;
    const unsigned short* kp2 = Kt + ((long)(n * 1024 + h * 64 + d)) * 4096 + sc * 512 + part * 128;
    float s = 0.f;
    for (int i = 0; i < 128; i += 8) {
        short8 v = *(const short8*)(kp2 + i);
#pragma unroll
        for (int e = 0; e < 8; ++e) s += bf2f((unsigned short)v[e]);
    }
    atomicAdd(Ksum + n * 1024 + h * 64 + d, s);
}

// ---------------- attn: V[n,l,h,m] = (sum_d Q[l,d]*KV[m,d]) / (Q[l,:]·Ksum + eps) ----------------
__global__ __launch_bounds__(256) void attn_kernel(const unsigned short* __restrict__ Qm,
                                                   const float* __restrict__ KV,
                                                   const float* __restrict__ Ksum,
                                                   unsigned short* __restrict__ Vbuf) {
    __shared__ unsigned short Qs[128 * 64];
    __shared__ unsigned short KVs[64 * 64];
    __shared__ float zin[128];
    __shared__ float ks[64];
    int b = blockIdx.x;
    int lc = b & 31, h = (b >> 5) & 15, n = b >> 9;
    int tid = threadIdx.x, lane = tid & 63, wave = tid >> 6;
    long l0 = (long)n * 4096 + lc * 128;

    const unsigned short* Qg = Qm + (l0 + (tid >> 3)) * 1024 + h * 64 + (tid & 7) * 8;
    char* QsB = (char*)Qs + (wave << 10);
#pragma unroll
    for (int it = 0; it < 4; ++it)
        async16(Qg + (long)it * 32 * 1024, QsB + it * 4096);

    const float* kvp = KV + (long)(n * 16 + h) * 4096;
    for (int i = tid * 4; i < 4096; i += 1024) {
        float4 v = *reinterpret_cast<const float4*>(kvp + i);
        short4v p;
        p[0] = (short)f2bf(v.x); p[1] = (short)f2bf(v.y);
        p[2] = (short)f2bf(v.z); p[3] = (short)f2bf(v.w);
        *(short4v*)(KVs + i) = p;
    }
    if (tid < 64) ks[tid] = Ksum[n * 1024 + h * 64 + tid];
    __syncthreads();

    if (tid < 128) {
        float den = 0.f;
        const unsigned short* qrow = Qs + tid * 64;
#pragma unroll
        for (int d = 0; d < 64; ++d) den += bf2f(qrow[d]) * ks[d];
        zin[tid] = 1.0f / (den + 1e-6f);
    }
    __syncthreads();

    const int lr = lane & 15, lk = (lane >> 4) * 8;
    f32x4 acc[2][4] = {};
#pragma unroll
    for (int kk = 0; kk < 2; ++kk) {
        short8 a0 = *(const short8*)(Qs + (wave * 32 + lr) * 64 + kk * 32 + lk);
        short8 a1 = *(const short8*)(Qs + (wave * 32 + 16 + lr) * 64 + kk * 32 + lk);
#pragma unroll
        for (int nn = 0; nn < 4; ++nn) {
            short8 bb = *(const short8*)(KVs + (nn * 16 + lr) * 64 + kk * 32 + lk);
            acc[0][nn] = MFMA16(a0, bb, acc[0][nn]);
            acc[1][nn] = MFMA16(a1, bb, acc[1][nn]);
        }
    }
#pragma unroll
    for (int mi = 0; mi < 2; ++mi)
#pragma unroll
        for (int nn = 0; nn < 4; ++nn)
#pragma unroll
            for (int j = 0; j < 4; ++j) {
                int rl = wave * 32 + mi * 16 + (lane >> 4) * 4 + j;
                int mcol = nn * 16 + lr;
                float v = acc[mi][nn][j] * zin[rl];
                Vbuf[(l0 + rl) * 1024 + h * 64 + mcol] = f2bf(v);
            }
}

extern "C" void kernel_launch(void* const* d_in, const int* in_sizes, int n_in,
                              void* d_out, int out_size, void* d_ws, size_t ws_size,
                              hipStream_t stream) {
    const float* queries = (const float*)d_in[0];
    const float* keys    = (const float*)d_in[1];
    const float* values  = (const float*)d_in[2];
    const float* Wq = (const float*)d_in[3];
    const float* bq = (const float*)d_in[4];
    const float* Wk = (const float*)d_in[5];
    const float* bk = (const float*)d_in[6];
    const float* Wv = (const float*)d_in[7];
    const float* bv = (const float*)d_in[8];
    const float* Wo = (const float*)d_in[9];
    const float* bo = (const float*)d_in[10];
    float* out = (float*)d_out;

    char* ws = (char*)d_ws;
    const size_t SZ = (size_t)16384 * 1024 * 2;  // 33.5 MB bf16 matrix
    const size_t WSZ = (size_t)1024 * 1024 * 2;  // 2 MB bf16 weight
    unsigned short* qb  = (unsigned short*)(ws);
    unsigned short* kb  = (unsigned short*)(ws + SZ);
    unsigned short* vb  = (unsigned short*)(ws + 2 * SZ);
    unsigned short* Wqb = (unsigned short*)(ws + 3 * SZ);
    unsigned short* Wkb = (unsigned short*)(ws + 3 * SZ + WSZ);
    unsigned short* Wvb = (unsigned short*)(ws + 3 * SZ + 2 * WSZ);
    unsigned short* Wob = (unsigned short*)(ws + 3 * SZ + 3 * WSZ);
    unsigned short* Qm  = (unsigned short*)(ws + 3 * SZ + 4 * WSZ);
    unsigned short* Kt  = (unsigned short*)(ws + 4 * SZ + 4 * WSZ);
    unsigned short* vT  = (unsigned short*)(ws + 5 * SZ + 4 * WSZ);
    float* KVf = (float*)(ws + 6 * SZ + 4 * WSZ);
    float* Ksf = (float*)(ws + 6 * SZ + 4 * WSZ + 1048576);
    unsigned short* Vbuf = qb;  // alias: qb dead after Q projection

    const int n4big = 16384 * 1024 / 4;
    const int n4w = 1024 * 1024 / 4;
    cvt_kernel<<<2048, 256, 0, stream>>>(queries, qb, n4big);
    cvt_kernel<<<2048, 256, 0, stream>>>(keys, kb, n4big);
    cvt_kernel<<<2048, 256, 0, stream>>>(values, vb, n4big);
    cvt_kernel<<<256, 256, 0, stream>>>(Wq, Wqb, n4w);
    cvt_kernel<<<256, 256, 0, stream>>>(Wk, Wkb, n4w);
    cvt_kernel<<<256, 256, 0, stream>>>(Wv, Wvb, n4w);
    cvt_kernel<<<256, 256, 0, stream>>>(Wo, Wob, n4w);

    gemm3p<0><<<512, 512, 0, stream>>>(qb, Wqb, bq, Qm);
    gemm3p<1><<<512, 512, 0, stream>>>(kb, Wkb, bk, Kt);
    gemm3p<2><<<512, 512, 0, stream>>>(vb, Wvb, bv, vT);

    hipMemsetAsync(KVf, 0, 1048576 + 16384, stream);
    kv_kernel<<<512, 256, 0, stream>>>(Kt, vT, KVf, Ksf);
    attn_kernel<<<2048, 256, 0, stream>>>(Qm, KVf, Ksf, Vbuf);

    gemm3p<3><<<512, 512, 0, stream>>>(Vbuf, Wob, bo, out);
}

// Round 5
// 279.290 us; speedup vs baseline: 1.2268x; 1.0505x over previous
//
#include <hip/hip_runtime.h>
#include <hip/hip_bf16.h>

typedef __attribute__((ext_vector_type(8))) short short8;
typedef __attribute__((ext_vector_type(4))) short short4v;
typedef __attribute__((ext_vector_type(4))) float f32x4;

#define MFMA16(a, b, c) __builtin_amdgcn_mfma_f32_16x16x32_bf16(a, b, c, 0, 0, 0)

__device__ __forceinline__ unsigned short f2bf(float f) {
    unsigned int u = __float_as_uint(f);
    unsigned int r = u + 0x7fffu + ((u >> 16) & 1u);
    return (unsigned short)(r >> 16);
}
__device__ __forceinline__ float bf2f(unsigned short h) {
    return __uint_as_float(((unsigned int)h) << 16);
}

__device__ __forceinline__ void async16(const void* g, void* l) {
    __builtin_amdgcn_global_load_lds(
        (const __attribute__((address_space(1))) unsigned int*)g,
        (__attribute__((address_space(3))) unsigned int*)l, 16, 0, 0);
}

#define S_BARRIER() asm volatile("s_barrier" ::: "memory")
#define SCHED_FENCE() __builtin_amdgcn_sched_barrier(0)

// ---------------- fp32 -> bf16 conversion ----------------
__global__ __launch_bounds__(256) void cvt_kernel(const float* __restrict__ in,
                                                  unsigned short* __restrict__ out,
                                                  int n4) {
    int i = blockIdx.x * 256 + threadIdx.x;
    int stride = gridDim.x * 256;
    for (; i < n4; i += stride) {
        float4 v = reinterpret_cast<const float4*>(in)[i];
        short4v p;
        p[0] = (short)f2bf(v.x); p[1] = (short)f2bf(v.y);
        p[2] = (short)f2bf(v.z); p[3] = (short)f2bf(v.w);
        reinterpret_cast<short4v*>(out)[i] = p;
    }
}

// ---------------- GEMM: C[M,1024] = A[M,1024] @ B[1024,1024]^T + bias ----------------
// BM=BN=256. Pipeline unit = half-K-step (K=32): A[256][32] + B[256][32] = 32KB,
// stored as 128 physical rows of 128B (two logical 32-k row-halves paired) with the
// R4-verified 3-bit XOR chunk swizzle (stored chunk = data chunk ^ (pr&7)) -> 0 conflicts.
// 4 LDS buffers (128KB): while computing unit u, stage unit u+2 into buf[(u+2)&3]
// (freed after u-2); boundary vmcnt(4) keeps u+2's 4 loads in flight, u+1 provably landed.
// 8 waves as 2M x 4N, per-wave output 128x64 (8x4 frag reps -> 42.7 FLOP/LDS-byte).
// Grid 64x4 = 256 blocks = exactly 1 block/CU, single occupancy round.
// MODE 0: elu+1, bf16 out, normal layout [M][1024]        (Q projection)
// MODE 1: elu+1, bf16 out, transposed [n*1024+col][4096]  (K projection -> Kt)
// MODE 2: plain, bf16 out, transposed                     (V projection -> vT)
// MODE 3: plain, fp32 out, normal layout                  (output projection)
template <int MODE>
__global__ __launch_bounds__(512, 2) void gemm4u(const unsigned short* __restrict__ A,
                                                 const unsigned short* __restrict__ B,
                                                 const float* __restrict__ bias,
                                                 void* __restrict__ out) {
    __shared__ __align__(16) char lds[4][32768];  // per unit: A 16KB + B 16KB

    const int tid = threadIdx.x;             // 0..511
    const int lane = tid & 63, wid = tid >> 6;
    const int wr = wid >> 2, wc = wid & 3;   // wave out: rows wr*128+[0,128), cols wc*64+[0,64)
    const int lr = lane & 15, lg = lane >> 4;

    // XCD-aware bijective swizzle (gridDim.x == 256)
    const int nwg = gridDim.x;
    const int bid = blockIdx.x;
    const int swz = (bid & 7) * (nwg >> 3) + (bid >> 3);
    const int bm = swz >> 2, bn = swz & 3;
    const long row0 = (long)bm * 256;
    const long col0 = (long)bn * 256;

    // ---- staging sources (pre-swizzled global addresses; LDS dest linear) ----
    // chunk s (0..1023): pr=s>>3, pc=s&7; data chunk pd = pc ^ (pr&7);
    // logical row = pr + 128*(pd>>2); k-chunk kc = pd&3.
    const unsigned short* asrc[2];
    const unsigned short* bsrc[2];
#pragma unroll
    for (int i = 0; i < 2; ++i) {
        int s = i * 512 + tid;
        int pr = s >> 3, pc = s & 7;
        int pd = pc ^ (pr & 7);
        int row = pr + 128 * (pd >> 2);
        int kc = pd & 3;
        asrc[i] = A + (row0 + row) * 1024 + kc * 8;
        bsrc[i] = B + (col0 + row) * 1024 + kc * 8;
    }
    const int dst = tid * 16;

#define STAGE(u) do { char* b_ = lds[(u) & 3];                        \
        async16(asrc[0] + (u) * 32, b_ + dst);                        \
        async16(asrc[1] + (u) * 32, b_ + 8192 + dst);                 \
        async16(bsrc[0] + (u) * 32, b_ + 16384 + dst);                \
        async16(bsrc[1] + (u) * 32, b_ + 24576 + dst); } while (0)

    // ---- ds_read offsets: logical (row, kc=lg); pr = row%128, rowhalf -> pd = half*4+lg ----
    int offA[8], offB[4];
#pragma unroll
    for (int m = 0; m < 8; ++m)
        offA[m] = (m * 16 + lr) * 128 + (((wr * 4 + lg) ^ (lr & 7)) << 4);
#pragma unroll
    for (int n = 0; n < 4; ++n)
        offB[n] = 16384 + ((wc & 1) * 64 + n * 16 + lr) * 128 +
                  ((((wc >> 1) * 4 + lg) ^ (lr & 7)) << 4);

    f32x4 acc[8][4] = {};

    // prologue: stage units 0,1; wait unit 0 (unit 1's 4 loads stay outstanding)
    STAGE(0); STAGE(1);
    asm volatile("s_waitcnt vmcnt(4)" ::: "memory");
    SCHED_FENCE();
    S_BARRIER();

#pragma unroll 4
    for (int u = 0; u < 32; ++u) {
        const char* base = lds[u & 3];
        short8 a[8], b[4];
        // group 1: a0-3 + b0-3 (8 reads), order pinned by fences
#pragma unroll
        for (int m = 0; m < 4; ++m) a[m] = *(const short8*)(base + offA[m]);
#pragma unroll
        for (int n = 0; n < 4; ++n) b[n] = *(const short8*)(base + offB[n]);
        SCHED_FENCE();
        // group 2: a4-7 (4 reads)
#pragma unroll
        for (int m = 4; m < 8; ++m) a[m] = *(const short8*)(base + offA[m]);
        SCHED_FENCE();
        if (u < 30) STAGE(u + 2);
        // first 8 ds_reads landed -> MFMA cluster 1
        asm volatile("s_waitcnt lgkmcnt(4)" ::: "memory");
        SCHED_FENCE();
        __builtin_amdgcn_s_setprio(1);
#pragma unroll
        for (int m = 0; m < 4; ++m)
#pragma unroll
            for (int n = 0; n < 4; ++n)
                acc[m][n] = MFMA16(a[m], b[n], acc[m][n]);
        __builtin_amdgcn_s_setprio(0);
        asm volatile("s_waitcnt lgkmcnt(0)" ::: "memory");
        SCHED_FENCE();
        __builtin_amdgcn_s_setprio(1);
#pragma unroll
        for (int m = 4; m < 8; ++m)
#pragma unroll
            for (int n = 0; n < 4; ++n)
                acc[m][n] = MFMA16(a[m], b[n], acc[m][n]);
        __builtin_amdgcn_s_setprio(0);
        SCHED_FENCE();
        // boundary: unit u+1 fully landed; unit u+2's 4 loads stay in flight
        if (u < 30) {
            asm volatile("s_waitcnt vmcnt(4)" ::: "memory");
        } else {
            asm volatile("s_waitcnt vmcnt(0)" ::: "memory");
        }
        SCHED_FENCE();
        S_BARRIER();
    }
#undef STAGE

    // ---- epilogue: row = row0 + wr*128 + m*16 + lg*4 + j ; col = col0 + wc*64 + n*16 + lr ----
    const int r4 = lg * 4;
#pragma unroll
    for (int m = 0; m < 8; ++m) {
#pragma unroll
        for (int n = 0; n < 4; ++n) {
            long col = col0 + wc * 64 + n * 16 + lr;
            float bcol = bias[col];
            long R0 = row0 + wr * 128 + m * 16 + r4;
            if (MODE == 0) {
                unsigned short* O = (unsigned short*)out;
#pragma unroll
                for (int j = 0; j < 4; ++j) {
                    float v = acc[m][n][j] + bcol;
                    v = v > 0.f ? v + 1.f : __expf(v);
                    O[(R0 + j) * 1024 + col] = f2bf(v);
                }
            } else if (MODE == 1 || MODE == 2) {
                unsigned short* O = (unsigned short*)out;
                long nb = R0 >> 12;
                long s = R0 & 4095;
                short4v pack;
#pragma unroll
                for (int j = 0; j < 4; ++j) {
                    float v = acc[m][n][j] + bcol;
                    if (MODE == 1) v = v > 0.f ? v + 1.f : __expf(v);
                    pack[j] = (short)f2bf(v);
                }
                *(short4v*)(O + ((nb << 10) + col) * 4096 + s) = pack;
            } else {
                float* O = (float*)out;
#pragma unroll
                for (int j = 0; j < 4; ++j)
                    O[(R0 + j) * 1024 + col] = acc[m][n][j] + bcol;
            }
        }
    }
}

// ---------------- KV[n,h,m,d] = sum_s vT[n*1024+h*64+m][s] * Kt[n*1024+h*64+d][s] ----------------
// also Ksum[n*1024+h*64+d] = sum_s Kt[...][s].  Grid: 4*16*8 = 512 blocks (S chunks of 512).
__global__ __launch_bounds__(256) void kv_kernel(const unsigned short* __restrict__ Kt,
                                                 const unsigned short* __restrict__ vT,
                                                 float* __restrict__ KV,
                                                 float* __restrict__ Ksum) {
    int b = blockIdx.x;
    int sc = b & 7, h = (b >> 3) & 15, n = b >> 7;
    const int tid = threadIdx.x, lane = tid & 63, wave = tid >> 6;
    long base = ((long)(n * 1024 + h * 64)) * 4096 + sc * 512;
    const unsigned short* Kp = Kt + base;
    const unsigned short* Vp = vT + base;
    const int lr = lane & 15, lk = (lane >> 4) * 8;

    f32x4 acc[4] = {};
    for (int s0 = 0; s0 < 512; s0 += 32) {
        short8 a = *(const short8*)(Vp + (long)(wave * 16 + lr) * 4096 + s0 + lk);
#pragma unroll
        for (int d4 = 0; d4 < 4; ++d4) {
            short8 bb = *(const short8*)(Kp + (long)(d4 * 16 + lr) * 4096 + s0 + lk);
            acc[d4] = MFMA16(a, bb, acc[d4]);
        }
    }
    float* KVb = KV + (long)(n * 16 + h) * 4096;
#pragma unroll
    for (int d4 = 0; d4 < 4; ++d4)
#pragma unroll
        for (int j = 0; j < 4; ++j) {
            int m = wave * 16 + (lane >> 4) * 4 + j;
            int d = d4 * 16 + lr;
            atomicAdd(KVb + m * 64 + d, acc[d4][j]);
        }
    // Ksum partial: thread t sums 128 s for column d = t&63
    int d = tid & 63, part = tid >> 6;
    const unsigned short* kp2 = Kt + ((long)(n * 1024 + h * 64 + d)) * 4096 + sc * 512 + part * 128;
    float s = 0.f;
    for (int i = 0; i < 128; i += 8) {
        short8 v = *(const short8*)(kp2 + i);
#pragma unroll
        for (int e = 0; e < 8; ++e) s += bf2f((unsigned short)v[e]);
    }
    atomicAdd(Ksum + n * 1024 + h * 64 + d, s);
}

// ---------------- attn: V[n,l,h,m] = (sum_d Q[l,d]*KV[m,d]) / (Q[l,:]·Ksum + eps) ----------------
__global__ __launch_bounds__(256) void attn_kernel(const unsigned short* __restrict__ Qm,
                                                   const float* __restrict__ KV,
                                                   const float* __restrict__ Ksum,
                                                   unsigned short* __restrict__ Vbuf) {
    __shared__ unsigned short Qs[128 * 64];
    __shared__ unsigned short KVs[64 * 64];
    __shared__ float zin[128];
    __shared__ float ks[64];
    int b = blockIdx.x;
    int lc = b & 31, h = (b >> 5) & 15, n = b >> 9;
    int tid = threadIdx.x, lane = tid & 63, wave = tid >> 6;
    long l0 = (long)n * 4096 + lc * 128;

    const unsigned short* Qg = Qm + (l0 + (tid >> 3)) * 1024 + h * 64 + (tid & 7) * 8;
    char* QsB = (char*)Qs + (wave << 10);
#pragma unroll
    for (int it = 0; it < 4; ++it)
        async16(Qg + (long)it * 32 * 1024, QsB + it * 4096);

    const float* kvp = KV + (long)(n * 16 + h) * 4096;
    for (int i = tid * 4; i < 4096; i += 1024) {
        float4 v = *reinterpret_cast<const float4*>(kvp + i);
        short4v p;
        p[0] = (short)f2bf(v.x); p[1] = (short)f2bf(v.y);
        p[2] = (short)f2bf(v.z); p[3] = (short)f2bf(v.w);
        *(short4v*)(KVs + i) = p;
    }
    if (tid < 64) ks[tid] = Ksum[n * 1024 + h * 64 + tid];
    __syncthreads();

    if (tid < 128) {
        float den = 0.f;
        const unsigned short* qrow = Qs + tid * 64;
#pragma unroll
        for (int d = 0; d < 64; ++d) den += bf2f(qrow[d]) * ks[d];
        zin[tid] = 1.0f / (den + 1e-6f);
    }
    __syncthreads();

    const int lr = lane & 15, lk = (lane >> 4) * 8;
    f32x4 acc[2][4] = {};
#pragma unroll
    for (int kk = 0; kk < 2; ++kk) {
        short8 a0 = *(const short8*)(Qs + (wave * 32 + lr) * 64 + kk * 32 + lk);
        short8 a1 = *(const short8*)(Qs + (wave * 32 + 16 + lr) * 64 + kk * 32 + lk);
#pragma unroll
        for (int nn = 0; nn < 4; ++nn) {
            short8 bb = *(const short8*)(KVs + (nn * 16 + lr) * 64 + kk * 32 + lk);
            acc[0][nn] = MFMA16(a0, bb, acc[0][nn]);
            acc[1][nn] = MFMA16(a1, bb, acc[1][nn]);
        }
    }
#pragma unroll
    for (int mi = 0; mi < 2; ++mi)
#pragma unroll
        for (int nn = 0; nn < 4; ++nn)
#pragma unroll
            for (int j = 0; j < 4; ++j) {
                int rl = wave * 32 + mi * 16 + (lane >> 4) * 4 + j;
                int mcol = nn * 16 + lr;
                float v = acc[mi][nn][j] * zin[rl];
                Vbuf[(l0 + rl) * 1024 + h * 64 + mcol] = f2bf(v);
            }
}

extern "C" void kernel_launch(void* const* d_in, const int* in_sizes, int n_in,
                              void* d_out, int out_size, void* d_ws, size_t ws_size,
                              hipStream_t stream) {
    const float* queries = (const float*)d_in[0];
    const float* keys    = (const float*)d_in[1];
    const float* values  = (const float*)d_in[2];
    const float* Wq = (const float*)d_in[3];
    const float* bq = (const float*)d_in[4];
    const float* Wk = (const float*)d_in[5];
    const float* bk = (const float*)d_in[6];
    const float* Wv = (const float*)d_in[7];
    const float* bv = (const float*)d_in[8];
    const float* Wo = (const float*)d_in[9];
    const float* bo = (const float*)d_in[10];
    float* out = (float*)d_out;

    char* ws = (char*)d_ws;
    const size_t SZ = (size_t)16384 * 1024 * 2;  // 33.5 MB bf16 matrix
    const size_t WSZ = (size_t)1024 * 1024 * 2;  // 2 MB bf16 weight
    unsigned short* qb  = (unsigned short*)(ws);
    unsigned short* kb  = (unsigned short*)(ws + SZ);
    unsigned short* vb  = (unsigned short*)(ws + 2 * SZ);
    unsigned short* Wqb = (unsigned short*)(ws + 3 * SZ);
    unsigned short* Wkb = (unsigned short*)(ws + 3 * SZ + WSZ);
    unsigned short* Wvb = (unsigned short*)(ws + 3 * SZ + 2 * WSZ);
    unsigned short* Wob = (unsigned short*)(ws + 3 * SZ + 3 * WSZ);
    unsigned short* Qm  = (unsigned short*)(ws + 3 * SZ + 4 * WSZ);
    unsigned short* Kt  = (unsigned short*)(ws + 4 * SZ + 4 * WSZ);
    unsigned short* vT  = (unsigned short*)(ws + 5 * SZ + 4 * WSZ);
    float* KVf = (float*)(ws + 6 * SZ + 4 * WSZ);
    float* Ksf = (float*)(ws + 6 * SZ + 4 * WSZ + 1048576);
    unsigned short* Vbuf = qb;  // alias: qb dead after Q projection

    const int n4big = 16384 * 1024 / 4;
    const int n4w = 1024 * 1024 / 4;
    cvt_kernel<<<2048, 256, 0, stream>>>(queries, qb, n4big);
    cvt_kernel<<<2048, 256, 0, stream>>>(keys, kb, n4big);
    cvt_kernel<<<2048, 256, 0, stream>>>(values, vb, n4big);
    cvt_kernel<<<256, 256, 0, stream>>>(Wq, Wqb, n4w);
    cvt_kernel<<<256, 256, 0, stream>>>(Wk, Wkb, n4w);
    cvt_kernel<<<256, 256, 0, stream>>>(Wv, Wvb, n4w);
    cvt_kernel<<<256, 256, 0, stream>>>(Wo, Wob, n4w);

    gemm4u<0><<<256, 512, 0, stream>>>(qb, Wqb, bq, Qm);
    gemm4u<1><<<256, 512, 0, stream>>>(kb, Wkb, bk, Kt);
    gemm4u<2><<<256, 512, 0, stream>>>(vb, Wvb, bv, vT);

    hipMemsetAsync(KVf, 0, 1048576 + 16384, stream);
    kv_kernel<<<512, 256, 0, stream>>>(Kt, vT, KVf, Ksf);
    attn_kernel<<<2048, 256, 0, stream>>>(Qm, KVf, Ksf, Vbuf);

    gemm4u<3><<<256, 512, 0, stream>>>(Vbuf, Wob, bo, out);
}

// Round 6
// 273.042 us; speedup vs baseline: 1.2549x; 1.0229x over previous
//
#include <hip/hip_runtime.h>
#include <hip/hip_bf16.h>

typedef __attribute__((ext_vector_type(8))) short short8;
typedef __attribute__((ext_vector_type(4))) short short4v;
typedef __attribute__((ext_vector_type(4))) float f32x4;

#define MFMA16(a, b, c) __builtin_amdgcn_mfma_f32_16x16x32_bf16(a, b, c, 0, 0, 0)

__device__ __forceinline__ unsigned short f2bf(float f) {
    unsigned int u = __float_as_uint(f);
    unsigned int r = u + 0x7fffu + ((u >> 16) & 1u);
    return (unsigned short)(r >> 16);
}
__device__ __forceinline__ float bf2f(unsigned short h) {
    return __uint_as_float(((unsigned int)h) << 16);
}

__device__ __forceinline__ void async16(const void* g, void* l) {
    __builtin_amdgcn_global_load_lds(
        (const __attribute__((address_space(1))) unsigned int*)g,
        (__attribute__((address_space(3))) unsigned int*)l, 16, 0, 0);
}

#define S_BARRIER() asm volatile("s_barrier" ::: "memory")
#define SCHED_FENCE() __builtin_amdgcn_sched_barrier(0)

// ---------------- fp32 -> bf16 conversion ----------------
__global__ __launch_bounds__(256) void cvt_kernel(const float* __restrict__ in,
                                                  unsigned short* __restrict__ out,
                                                  int n4) {
    int i = blockIdx.x * 256 + threadIdx.x;
    int stride = gridDim.x * 256;
    for (; i < n4; i += stride) {
        float4 v = reinterpret_cast<const float4*>(in)[i];
        short4v p;
        p[0] = (short)f2bf(v.x); p[1] = (short)f2bf(v.y);
        p[2] = (short)f2bf(v.z); p[3] = (short)f2bf(v.w);
        reinterpret_cast<short4v*>(out)[i] = p;
    }
}

// ---------------- 8-phase GEMM: C[M,1024] = A[M,1024] @ B[1024,1024]^T + bias ----------
// m201-template port. BM=BN=256, BK=64, 2 K-tiles/iter, 8 iters (K=1024).
// 8 waves (2M x 4N), per-wave 128x64 out. LDS 2 bufs x 64KB (buf0=even kt, buf1=odd).
// A stored as m-quadrants Aq0 (frag rows m0-3 of both wave-rows), Aq1 (m4-7);
// B as two 128-col halves. All [128 rows][64 k] with 3-bit XOR chunk swizzle
// (stored chunk = data chunk ^ (row&7)) -> 0 bank conflicts (verified R4/R5).
// Per phase: ds_reads (4-8 b128) | stage 1 half (2 gll) | barrier | lgkm0 |
// setprio1 | 16 MFMA | setprio0 | barrier. vmcnt(4) only at phases 4 & 8.
// Stage stagger (race-free, every staged region >=1 barrier after last read):
//  P1: buf1:B1(2t+1)  P2: buf1:Aq1(2t+1)  P3: buf0:Aq0(2t+2)  P4: buf0:B0(2t+2)+G2
//  P5: buf0:B1(2t+2)  P6: buf0:Aq1(2t+2)  P7: buf1:Aq0(2t+3)  P8: buf1:B0(2t+3)+G1
// MODE 0: elu+1, bf16 out, normal layout        (Q projection)
// MODE 1: elu+1, bf16 out, transposed           (K projection -> Kt)
// MODE 2: plain, bf16 out, transposed           (V projection -> vT)
// MODE 3: plain, fp32 out, normal layout        (output projection)
template <int MODE>
__global__ __launch_bounds__(512, 2) void gemm8p(const unsigned short* __restrict__ A,
                                                 const unsigned short* __restrict__ B,
                                                 const float* __restrict__ bias,
                                                 void* __restrict__ out) {
    __shared__ __align__(16) char lds[131072];  // 2 bufs x (Aq0 16K, Aq1 16K, B0 16K, B1 16K)

    const int tid = threadIdx.x;             // 0..511
    const int lane = tid & 63, wid = tid >> 6;
    const int wr = wid >> 2, wc = wid & 3;   // wave out: rows wr*128, cols wc*64
    const int lr = lane & 15, lg = lane >> 4;

    // XCD-aware bijective swizzle (gridDim.x == 256)
    const int nwg = gridDim.x;
    const int bid = blockIdx.x;
    const int swz = (bid & 7) * (nwg >> 3) + (bid >> 3);
    const int bm = swz >> 2, bn = swz & 3;
    const long row0 = (long)bm * 256;
    const long col0 = (long)bn * 256;

    // ---- staging sources (pre-swizzled; LDS dest linear) ----
    // half = [128 phys rows][64 k]; chunk s = g*512+tid: pr=s>>3, dc=(s&7)^(pr&7)
    const unsigned short* srcA[2];
    const unsigned short* srcB[2];
    int dstOff[2];
#pragma unroll
    for (int g = 0; g < 2; ++g) {
        int s = g * 512 + tid;
        int pr = s >> 3;
        int dc = (s & 7) ^ (pr & 7);
        // A quadrant q phys row pr -> global row (pr&63) + 64*q + 128*(pr>>6)
        srcA[g] = A + (row0 + (pr & 63) + 128 * (pr >> 6)) * 1024 + dc * 8;
        // B half h phys row pr -> global row col0 + h*128 + pr
        srcB[g] = B + (col0 + pr) * 1024 + dc * 8;
        dstOff[g] = s * 16;
    }

    // STG_AQ(bufsel, q, kt); STG_BH(bufsel, h, kt)
#define STG_AQ(BB, Q, KT) do {                                                  \
        async16(srcA[0] + (Q) * 65536 + (KT) * 64,                              \
                lds + (BB) * 65536 + (Q) * 16384 + dstOff[0]);                  \
        async16(srcA[1] + (Q) * 65536 + (KT) * 64,                              \
                lds + (BB) * 65536 + (Q) * 16384 + dstOff[1]); } while (0)
#define STG_BH(BB, H, KT) do {                                                  \
        async16(srcB[0] + (H) * 131072 + (KT) * 64,                             \
                lds + (BB) * 65536 + 32768 + (H) * 16384 + dstOff[0]);          \
        async16(srcB[1] + (H) * 131072 + (KT) * 64,                             \
                lds + (BB) * 65536 + 32768 + (H) * 16384 + dstOff[1]); } while (0)

    // ---- ds_read byte offsets ----
    // A frag m (0..7): quadrant q=m>>2, phys row (m&3)*16 + lr + 64*wr
    // B frag n: half wc>>1, phys row (wc&1)*64 + n*16 + lr
    // chunk(kk) = ((kk*4+lg) ^ (lr&7)) * 16 bytes
    const int ch0 = (((0 * 4 + lg) ^ (lr & 7)) << 4);
    const int ch1 = (((1 * 4 + lg) ^ (lr & 7)) << 4);
    const int aB0 = (64 * wr + lr) * 128 + ch0;           // + q*16384 + (m&3)*2048
    const int aB1 = (64 * wr + lr) * 128 + ch1;
    const int bB0 = 32768 + (wc >> 1) * 16384 + ((wc & 1) * 64 + lr) * 128 + ch0;  // + n*2048
    const int bB1 = 32768 + (wc >> 1) * 16384 + ((wc & 1) * 64 + lr) * 128 + ch1;

    f32x4 acc[8][4] = {};
    short8 b0[4], b1[4];

#define GATE4() do { asm volatile("s_waitcnt vmcnt(4)" ::: "memory"); SCHED_FENCE(); } while (0)
#define GATE0() do { asm volatile("s_waitcnt vmcnt(0)" ::: "memory"); SCHED_FENCE(); } while (0)
#define MFMA_BLOCK(MB, BV) do {                                                 \
        S_BARRIER();                                                            \
        asm volatile("s_waitcnt lgkmcnt(0)" ::: "memory");                      \
        SCHED_FENCE();                                                          \
        __builtin_amdgcn_s_setprio(1);                                          \
        _Pragma("unroll") for (int m = 0; m < 4; ++m)                           \
            _Pragma("unroll") for (int n = 0; n < 4; ++n)                       \
                acc[(MB) + m][n] = MFMA16(a[m], BV[n], acc[(MB) + m][n]);       \
        __builtin_amdgcn_s_setprio(0);                                          \
        SCHED_FENCE();                                                          \
        S_BARRIER(); } while (0)
#define LOAD_A(BUFB, ABASE, Q) do {                                             \
        _Pragma("unroll") for (int m = 0; m < 4; ++m)                           \
            a[m] = *(const short8*)(lds + (BUFB) + (Q) * 16384 + (ABASE) + m * 2048); } while (0)
#define LOAD_B(BUFB, BBASE, BV) do {                                            \
        _Pragma("unroll") for (int n = 0; n < 4; ++n)                           \
            BV[n] = *(const short8*)(lds + (BUFB) + (BBASE) + n * 2048); } while (0)

    // ---- prologue: kt0 -> buf0 (all 4 halves), kt1 -> buf1 (Aq0,B0) ----
    STG_AQ(0, 0, 0); STG_BH(0, 0, 0); STG_BH(0, 1, 0); STG_AQ(0, 1, 0);
    STG_AQ(1, 0, 1); STG_BH(1, 0, 1);
    GATE4();          // kt0 resident; kt1's 4 loads in flight
    S_BARRIER();

#pragma unroll 1
    for (int t = 0; t < 7; ++t) {
        const int ktA = 2 * t + 1, ktB = 2 * t + 2, ktC = 2 * t + 3;
        { // P1: buf0, kk0, m0-3, load b0
            short8 a[4];
            LOAD_B(0, bB0, b0); LOAD_A(0, aB0, 0);
            STG_BH(1, 1, ktA);
            MFMA_BLOCK(0, b0);
        }
        { // P2: buf0, kk1, m0-3, load b1
            short8 a[4];
            LOAD_B(0, bB1, b1); LOAD_A(0, aB1, 0);
            STG_AQ(1, 1, ktA);
            MFMA_BLOCK(0, b1);
        }
        { // P3: buf0, kk0, m4-7
            short8 a[4];
            LOAD_A(0, aB0, 1);
            STG_AQ(0, 0, ktB);
            MFMA_BLOCK(4, b0);
        }
        { // P4: buf0, kk1, m4-7  + G2
            short8 a[4];
            LOAD_A(0, aB1, 1);
            STG_BH(0, 0, ktB);
            GATE4();
            MFMA_BLOCK(4, b1);
        }
        { // P5: buf1, kk0, m0-3, load b0
            short8 a[4];
            LOAD_B(65536, bB0, b0); LOAD_A(65536, aB0, 0);
            STG_BH(0, 1, ktB);
            MFMA_BLOCK(0, b0);
        }
        { // P6: buf1, kk1, m0-3, load b1
            short8 a[4];
            LOAD_B(65536, bB1, b1); LOAD_A(65536, aB1, 0);
            STG_AQ(0, 1, ktB);
            MFMA_BLOCK(0, b1);
        }
        { // P7: buf1, kk0, m4-7
            short8 a[4];
            LOAD_A(65536, aB0, 1);
            STG_AQ(1, 0, ktC);
            MFMA_BLOCK(4, b0);
        }
        { // P8: buf1, kk1, m4-7  + G1
            short8 a[4];
            LOAD_A(65536, aB1, 1);
            STG_BH(1, 0, ktC);
            GATE4();
            MFMA_BLOCK(4, b1);
        }
    }
    // ---- peeled last iter (t=7): finish kt15 staging, no further prefetch ----
    {
        { short8 a[4]; LOAD_B(0, bB0, b0); LOAD_A(0, aB0, 0); STG_BH(1, 1, 15); MFMA_BLOCK(0, b0); }
        { short8 a[4]; LOAD_B(0, bB1, b1); LOAD_A(0, aB1, 0); STG_AQ(1, 1, 15); MFMA_BLOCK(0, b1); }
        { short8 a[4]; LOAD_A(0, aB0, 1); MFMA_BLOCK(4, b0); }
        { short8 a[4]; LOAD_A(0, aB1, 1); GATE0(); MFMA_BLOCK(4, b1); }
        { short8 a[4]; LOAD_B(65536, bB0, b0); LOAD_A(65536, aB0, 0); MFMA_BLOCK(0, b0); }
        { short8 a[4]; LOAD_B(65536, bB1, b1); LOAD_A(65536, aB1, 0); MFMA_BLOCK(0, b1); }
        { short8 a[4]; LOAD_A(65536, aB0, 1); MFMA_BLOCK(4, b0); }
        { short8 a[4]; LOAD_A(65536, aB1, 1); MFMA_BLOCK(4, b1); }
    }
#undef STG_AQ
#undef STG_BH
#undef GATE4
#undef GATE0
#undef MFMA_BLOCK
#undef LOAD_A
#undef LOAD_B

    // ---- epilogue: row = row0 + wr*128 + m*16 + lg*4 + j ; col = col0 + wc*64 + n*16 + lr ----
    const int r4 = lg * 4;
#pragma unroll
    for (int m = 0; m < 8; ++m) {
#pragma unroll
        for (int n = 0; n < 4; ++n) {
            long col = col0 + wc * 64 + n * 16 + lr;
            float bcol = bias[col];
            long R0 = row0 + wr * 128 + m * 16 + r4;
            if (MODE == 0) {
                unsigned short* O = (unsigned short*)out;
#pragma unroll
                for (int j = 0; j < 4; ++j) {
                    float v = acc[m][n][j] + bcol;
                    v = v > 0.f ? v + 1.f : __expf(v);
                    O[(R0 + j) * 1024 + col] = f2bf(v);
                }
            } else if (MODE == 1 || MODE == 2) {
                unsigned short* O = (unsigned short*)out;
                long nb = R0 >> 12;
                long s = R0 & 4095;
                short4v pack;
#pragma unroll
                for (int j = 0; j < 4; ++j) {
                    float v = acc[m][n][j] + bcol;
                    if (MODE == 1) v = v > 0.f ? v + 1.f : __expf(v);
                    pack[j] = (short)f2bf(v);
                }
                *(short4v*)(O + ((nb << 10) + col) * 4096 + s) = pack;
            } else {
                float* O = (float*)out;
#pragma unroll
                for (int j = 0; j < 4; ++j)
                    O[(R0 + j) * 1024 + col] = acc[m][n][j] + bcol;
            }
        }
    }
}

// ---------------- KV[n,h,m,d] = sum_s vT[n*1024+h*64+m][s] * Kt[n*1024+h*64+d][s] ----------------
// also Ksum[n*1024+h*64+d] = sum_s Kt[...][s].  Grid: 4*16*8 = 512 blocks (S chunks of 512).
__global__ __launch_bounds__(256) void kv_kernel(const unsigned short* __restrict__ Kt,
                                                 const unsigned short* __restrict__ vT,
                                                 float* __restrict__ KV,
                                                 float* __restrict__ Ksum) {
    int b = blockIdx.x;
    int sc = b & 7, h = (b >> 3) & 15, n = b >> 7;
    const int tid = threadIdx.x, lane = tid & 63, wave = tid >> 6;
    long base = ((long)(n * 1024 + h * 64)) * 4096 + sc * 512;
    const unsigned short* Kp = Kt + base;
    const unsigned short* Vp = vT + base;
    const int lr = lane & 15, lk = (lane >> 4) * 8;

    f32x4 acc[4] = {};
    for (int s0 = 0; s0 < 512; s0 += 32) {
        short8 a = *(const short8*)(Vp + (long)(wave * 16 + lr) * 4096 + s0 + lk);
#pragma unroll
        for (int d4 = 0; d4 < 4; ++d4) {
            short8 bb = *(const short8*)(Kp + (long)(d4 * 16 + lr) * 4096 + s0 + lk);
            acc[d4] = MFMA16(a, bb, acc[d4]);
        }
    }
    float* KVb = KV + (long)(n * 16 + h) * 4096;
#pragma unroll
    for (int d4 = 0; d4 < 4; ++d4)
#pragma unroll
        for (int j = 0; j < 4; ++j) {
            int m = wave * 16 + (lane >> 4) * 4 + j;
            int d = d4 * 16 + lr;
            atomicAdd(KVb + m * 64 + d, acc[d4][j]);
        }
    // Ksum partial: thread t sums 128 s for column d = t&63
    int d = tid & 63, part = tid >> 6;
    const unsigned short* kp2 = Kt + ((long)(n * 1024 + h * 64 + d)) * 4096 + sc * 512 + part * 128;
    float s = 0.f;
    for (int i = 0; i < 128; i += 8) {
        short8 v = *(const short8*)(kp2 + i);
#pragma unroll
        for (int e = 0; e < 8; ++e) s += bf2f((unsigned short)v[e]);
    }
    atomicAdd(Ksum + n * 1024 + h * 64 + d, s);
}

// ---------------- attn: V[n,l,h,m] = (sum_d Q[l,d]*KV[m,d]) / (Q[l,:]·Ksum + eps) ----------------
__global__ __launch_bounds__(256) void attn_kernel(const unsigned short* __restrict__ Qm,
                                                   const float* __restrict__ KV,
                                                   const float* __restrict__ Ksum,
                                                   unsigned short* __restrict__ Vbuf) {
    __shared__ unsigned short Qs[128 * 64];
    __shared__ unsigned short KVs[64 * 64];
    __shared__ float zin[128];
    __shared__ float ks[64];
    int b = blockIdx.x;
    int lc = b & 31, h = (b >> 5) & 15, n = b >> 9;
    int tid = threadIdx.x, lane = tid & 63, wave = tid >> 6;
    long l0 = (long)n * 4096 + lc * 128;

    const unsigned short* Qg = Qm + (l0 + (tid >> 3)) * 1024 + h * 64 + (tid & 7) * 8;
    char* QsB = (char*)Qs + (wave << 10);
#pragma unroll
    for (int it = 0; it < 4; ++it)
        async16(Qg + (long)it * 32 * 1024, QsB + it * 4096);

    const float* kvp = KV + (long)(n * 16 + h) * 4096;
    for (int i = tid * 4; i < 4096; i += 1024) {
        float4 v = *reinterpret_cast<const float4*>(kvp + i);
        short4v p;
        p[0] = (short)f2bf(v.x); p[1] = (short)f2bf(v.y);
        p[2] = (short)f2bf(v.z); p[3] = (short)f2bf(v.w);
        *(short4v*)(KVs + i) = p;
    }
    if (tid < 64) ks[tid] = Ksum[n * 1024 + h * 64 + tid];
    __syncthreads();

    if (tid < 128) {
        float den = 0.f;
        const unsigned short* qrow = Qs + tid * 64;
#pragma unroll
        for (int d = 0; d < 64; ++d) den += bf2f(qrow[d]) * ks[d];
        zin[tid] = 1.0f / (den + 1e-6f);
    }
    __syncthreads();

    const int lr = lane & 15, lk = (lane >> 4) * 8;
    f32x4 acc[2][4] = {};
#pragma unroll
    for (int kk = 0; kk < 2; ++kk) {
        short8 a0 = *(const short8*)(Qs + (wave * 32 + lr) * 64 + kk * 32 + lk);
        short8 a1 = *(const short8*)(Qs + (wave * 32 + 16 + lr) * 64 + kk * 32 + lk);
#pragma unroll
        for (int nn = 0; nn < 4; ++nn) {
            short8 bb = *(const short8*)(KVs + (nn * 16 + lr) * 64 + kk * 32 + lk);
            acc[0][nn] = MFMA16(a0, bb, acc[0][nn]);
            acc[1][nn] = MFMA16(a1, bb, acc[1][nn]);
        }
    }
#pragma unroll
    for (int mi = 0; mi < 2; ++mi)
#pragma unroll
        for (int nn = 0; nn < 4; ++nn)
#pragma unroll
            for (int j = 0; j < 4; ++j) {
                int rl = wave * 32 + mi * 16 + (lane >> 4) * 4 + j;
                int mcol = nn * 16 + lr;
                float v = acc[mi][nn][j] * zin[rl];
                Vbuf[(l0 + rl) * 1024 + h * 64 + mcol] = f2bf(v);
            }
}

extern "C" void kernel_launch(void* const* d_in, const int* in_sizes, int n_in,
                              void* d_out, int out_size, void* d_ws, size_t ws_size,
                              hipStream_t stream) {
    const float* queries = (const float*)d_in[0];
    const float* keys    = (const float*)d_in[1];
    const float* values  = (const float*)d_in[2];
    const float* Wq = (const float*)d_in[3];
    const float* bq = (const float*)d_in[4];
    const float* Wk = (const float*)d_in[5];
    const float* bk = (const float*)d_in[6];
    const float* Wv = (const float*)d_in[7];
    const float* bv = (const float*)d_in[8];
    const float* Wo = (const float*)d_in[9];
    const float* bo = (const float*)d_in[10];
    float* out = (float*)d_out;

    char* ws = (char*)d_ws;
    const size_t SZ = (size_t)16384 * 1024 * 2;  // 33.5 MB bf16 matrix
    const size_t WSZ = (size_t)1024 * 1024 * 2;  // 2 MB bf16 weight
    unsigned short* qb  = (unsigned short*)(ws);
    unsigned short* kb  = (unsigned short*)(ws + SZ);
    unsigned short* vb  = (unsigned short*)(ws + 2 * SZ);
    unsigned short* Wqb = (unsigned short*)(ws + 3 * SZ);
    unsigned short* Wkb = (unsigned short*)(ws + 3 * SZ + WSZ);
    unsigned short* Wvb = (unsigned short*)(ws + 3 * SZ + 2 * WSZ);
    unsigned short* Wob = (unsigned short*)(ws + 3 * SZ + 3 * WSZ);
    unsigned short* Qm  = (unsigned short*)(ws + 3 * SZ + 4 * WSZ);
    unsigned short* Kt  = (unsigned short*)(ws + 4 * SZ + 4 * WSZ);
    unsigned short* vT  = (unsigned short*)(ws + 5 * SZ + 4 * WSZ);
    float* KVf = (float*)(ws + 6 * SZ + 4 * WSZ);
    float* Ksf = (float*)(ws + 6 * SZ + 4 * WSZ + 1048576);
    unsigned short* Vbuf = qb;  // alias: qb dead after Q projection

    const int n4big = 16384 * 1024 / 4;
    const int n4w = 1024 * 1024 / 4;
    cvt_kernel<<<2048, 256, 0, stream>>>(queries, qb, n4big);
    cvt_kernel<<<2048, 256, 0, stream>>>(keys, kb, n4big);
    cvt_kernel<<<2048, 256, 0, stream>>>(values, vb, n4big);
    cvt_kernel<<<256, 256, 0, stream>>>(Wq, Wqb, n4w);
    cvt_kernel<<<256, 256, 0, stream>>>(Wk, Wkb, n4w);
    cvt_kernel<<<256, 256, 0, stream>>>(Wv, Wvb, n4w);
    cvt_kernel<<<256, 256, 0, stream>>>(Wo, Wob, n4w);

    gemm8p<0><<<256, 512, 0, stream>>>(qb, Wqb, bq, Qm);
    gemm8p<1><<<256, 512, 0, stream>>>(kb, Wkb, bk, Kt);
    gemm8p<2><<<256, 512, 0, stream>>>(vb, Wvb, bv, vT);

    hipMemsetAsync(KVf, 0, 1048576 + 16384, stream);
    kv_kernel<<<512, 256, 0, stream>>>(Kt, vT, KVf, Ksf);
    attn_kernel<<<2048, 256, 0, stream>>>(Qm, KVf, Ksf, Vbuf);

    gemm8p<3><<<256, 512, 0, stream>>>(Vbuf, Wob, bo, out);
}